// Round 1
// 566.334 us; speedup vs baseline: 1.0218x; 1.0218x over previous
//
#include <hip/hip_runtime.h>

#define NB 8
#define NA 100000
#define NC 90
#define MAXDET 100
#define KCAND 2048
#define NBINS 4096
#define NBLK 13        // hist/compact blocks per image
#define BLK_ANCH 8000  // anchors per hist/compact block
#define ABLK 64        // anchors per score_box block (22.5 KB LDS -> 7 blocks/CU)
#define MASK_WORDS 32  // u64 words per mask row (2048 bits)
#define SROWS 504      // mask rows staged in LDS by k_scan (126 KB)
#define CONF 0.25f
#define IOUT 0.45f

// ---- workspace layout (bytes), total ~10.5 MiB ----
static constexpr size_t OFF_SCORE = 0;                                           // NB*NA f32
static constexpr size_t OFF_LABEL = OFF_SCORE + (size_t)NB * NA * 4;             // NB*NA u8
static constexpr size_t OFF_HROWS = OFF_LABEL + (size_t)NB * NA;                 // NB*NBLK*NBINS u32
static constexpr size_t OFF_THR   = OFF_HROWS + (size_t)NB * NBLK * NBINS * 4;   // NB u32 (pad 64)
static constexpr size_t OFF_CNT   = OFF_THR + 64;                                // NB u32 (pad 64)
static constexpr size_t OFF_CKEY  = OFF_CNT + 64;                                // NB*KCAND u64
static constexpr size_t OFF_SSC   = OFF_CKEY + (size_t)NB * KCAND * 8;           // NB*KCAND f32
static constexpr size_t OFF_SLAB  = OFF_SSC + (size_t)NB * KCAND * 4;            // NB*KCAND i32
static constexpr size_t OFF_SBOX  = OFF_SLAB + (size_t)NB * KCAND * 4;           // NB*KCAND float4
static constexpr size_t OFF_MASK  = OFF_SBOX + (size_t)NB * KCAND * 16;          // NB*KCAND*32 u64

__device__ __forceinline__ float4 decode_clip(float4 a, float4 r) {
#pragma clang fp contract(off)
    // a = (y1,x1,y2,x2) anchor; r = (dy,dx,dh,dw)
    float yca = (a.x + a.z) * 0.5f;
    float xca = (a.y + a.w) * 0.5f;
    float ha  = a.z - a.x;
    float wa  = a.w - a.y;
    float w   = expf(r.w) * wa;
    float h   = expf(r.z) * ha;
    float yc  = r.x * ha + yca;
    float xc  = r.y * wa + xca;
    float x1  = xc - w * 0.5f, y1 = yc - h * 0.5f;
    float x2  = xc + w * 0.5f, y2 = yc + h * 0.5f;
    x1 = fminf(fmaxf(x1, 0.0f), 512.0f);
    x2 = fminf(fmaxf(x2, 0.0f), 512.0f);
    y1 = fminf(fmaxf(y1, 0.0f), 512.0f);
    y2 = fminf(fmaxf(y2, 0.0f), 512.0f);
    return make_float4(x1, y1, x2, y2);
}

// LDS-transpose score kernel. Sigmoid is strictly monotonic, so the per-class
// reduction runs on RAW LOGITS via an order-preserving bit transform (3 VALU ops
// per element instead of expf+IEEE-div ~35); exactly ONE sigmoid per anchor is
// computed on the winning logit with the same verified formula, so all scores
// are bit-identical to the per-class-sigmoid version.
__global__ __launch_bounds__(256) void k_score_box(const float* __restrict__ cls,
                                                   float* __restrict__ ws_score,
                                                   unsigned char* __restrict__ ws_label) {
    __shared__ float tile[ABLK * NC];  // 22.5 KB
    int t = threadIdx.x;
    const float4* g4 = (const float4*)(cls + (size_t)blockIdx.x * (ABLK * NC));
    float4* t4 = (float4*)tile;
#pragma unroll
    for (int i = t; i < ABLK * NC / 4; i += 256) t4[i] = g4[i];
    __syncthreads();

    int la = t >> 2, h = t & 3;
    int off = h * 22 + (h < 2 ? h : 2);  // 0,23,46,68
    int len = (h < 2) ? 23 : 22;
    const float* row = tile + la * NC + off;
    // order-preserving unsigned encoding of float: pos -> u|0x80000000, neg -> ~u
    unsigned bord = 0u;
    int bci = 0;
    for (int i = 0; i < len; ++i) {
        unsigned u = __float_as_uint(row[i]);
        unsigned ord = u ^ (0x80000000u | (unsigned)((int)u >> 31));
        if (ord > bord) { bord = ord; bci = off + i; }  // strict > keeps first (lowest class)
    }
    unsigned long long best =
        ((unsigned long long)bord << 32) | (unsigned long long)(unsigned)(NC - 1 - bci);
    unsigned long long o = __shfl_xor(best, 1, 64);
    if (o > best) best = o;
    o = __shfl_xor(best, 2, 64);
    if (o > best) best = o;
    if (h == 0) {
        int a = blockIdx.x * ABLK + la;
        unsigned ordv = (unsigned)(best >> 32);
        unsigned u = (ordv & 0x80000000u) ? (ordv ^ 0x80000000u) : ~ordv;
        float x = __uint_as_float(u);
        float s = 1.0f / (1.0f + expf(-x));  // same formula as verified rounds 2-4
        ws_score[a] = s;
        ws_label[a] = (unsigned char)(NC - 1 - (unsigned)(best & 0xFFFFFFFFu));
    }
}

// Per-block LDS histogram, full-row writeout (no global atomics).
__global__ __launch_bounds__(256) void k_hist(const float* __restrict__ ws_score,
                                              unsigned* __restrict__ hrows) {
    __shared__ unsigned h[NBINS];
    int b = blockIdx.y, blk = blockIdx.x, tid = threadIdx.x;
    for (int i = tid; i < NBINS; i += 256) h[i] = 0u;
    __syncthreads();
    int base = blk * BLK_ANCH;
    int lim = min(BLK_ANCH, NA - base);
    const float* sc = ws_score + (size_t)b * NA + base;
    for (int i = tid; i < lim; i += 256) {
        float s = sc[i];
        if (s > CONF) {
            int bin = min((int)(s * (float)NBINS), NBINS - 1);
            atomicAdd(&h[bin], 1u);
        }
    }
    __syncthreads();
    unsigned* row = hrows + ((size_t)b * NBLK + blk) * NBINS;
    for (int i = tid; i < NBINS; i += 256) row[i] = h[i];
}

// One block per image: reduce rows, min bin with suffix-count <= KCAND; zero cnt.
__global__ __launch_bounds__(256) void k_thresh(const unsigned* __restrict__ hrows,
                                                unsigned* __restrict__ thr_bin,
                                                unsigned* __restrict__ cnt) {
    __shared__ unsigned h[NBINS];
    __shared__ unsigned chunk[256];
    __shared__ int bstar;
    int b = blockIdx.x, t = threadIdx.x;
    for (int i = t; i < NBINS; i += 256) {
        unsigned s = 0;
        for (int r = 0; r < NBLK; ++r) s += hrows[((size_t)b * NBLK + r) * NBINS + i];
        h[i] = s;
    }
    if (t == 0) { bstar = NBINS - 1; cnt[b] = 0u; }
    __syncthreads();
    unsigned s = 0;
    for (int j = 0; j < 16; ++j) s += h[t * 16 + j];
    chunk[t] = s;
    __syncthreads();
    unsigned U = 0;
    for (int j = t + 1; j < 256; ++j) U += chunk[j];
    unsigned run = U;
    int cand = NBINS;
    for (int j = 15; j >= 0; --j) {
        run += h[t * 16 + j];
        if (run <= (unsigned)KCAND) cand = t * 16 + j;
    }
    if (cand < NBINS) atomicMin(&bstar, cand);
    __syncthreads();
    if (t == 0) thr_bin[b] = (unsigned)bstar;
}

// Block-aggregated compaction: writes packed keys only (idx embedded). One atomic/block.
__global__ __launch_bounds__(256) void k_compact(const float* __restrict__ ws_score,
                                                 const unsigned* __restrict__ thr_bin,
                                                 unsigned* __restrict__ cnt,
                                                 unsigned long long* __restrict__ ckey) {
    __shared__ unsigned scan[256];
    __shared__ unsigned base_s;
    int b = blockIdx.y, blk = blockIdx.x, t = threadIdx.x;
    int base = blk * BLK_ANCH;
    int lim = min(BLK_ANCH, NA - base);
    size_t ibase = (size_t)b * NA + base;
    unsigned thr = thr_bin[b];

    unsigned c = 0;
    for (int i = t; i < lim; i += 256) {
        float s = ws_score[ibase + i];
        if (s > CONF) {
            int bin = min((int)(s * (float)NBINS), NBINS - 1);
            if ((unsigned)bin >= thr) c++;
        }
    }
    scan[t] = c;
    __syncthreads();
    for (int off = 1; off < 256; off <<= 1) {
        unsigned v = (t >= off) ? scan[t - off] : 0u;
        __syncthreads();
        scan[t] += v;
        __syncthreads();
    }
    if (t == 255) base_s = atomicAdd(&cnt[b], scan[255]);
    __syncthreads();
    unsigned pos = base_s + scan[t] - c;
    for (int i = t; i < lim; i += 256) {
        float s = ws_score[ibase + i];
        if (s > CONF) {
            int bin = min((int)(s * (float)NBINS), NBINS - 1);
            if ((unsigned)bin >= thr) {
                unsigned p = pos++;
                if (p < (unsigned)KCAND) {
                    int n = base + i;
                    ckey[(size_t)b * KCAND + p] =
                        ((unsigned long long)__float_as_uint(s) << 32) |
                        (unsigned long long)(0xFFFFFFFFu - (unsigned)n);
                }
            }
        }
    }
}

// One 1024-thread block per image: bitonic sort 2048 keys descending (16 waves to
// amortize the 66 barriers), then decode surviving boxes.
__global__ __launch_bounds__(1024) void k_sortdecode(const unsigned long long* __restrict__ ckey,
                                                     const unsigned* __restrict__ cnt,
                                                     const unsigned char* __restrict__ ws_label,
                                                     const float* __restrict__ reg,
                                                     const float* __restrict__ anc,
                                                     float* __restrict__ sscore,
                                                     int* __restrict__ slab,
                                                     float4* __restrict__ sbox) {
    __shared__ unsigned long long key[KCAND];  // 16 KB
    int b = blockIdx.x, t = threadIdx.x;
    unsigned M = min(cnt[b], (unsigned)KCAND);
    for (int i = t; i < KCAND; i += 1024)
        key[i] = (i < (int)M) ? ckey[(size_t)b * KCAND + i] : 0ULL;
    __syncthreads();
    for (int k = 2; k <= KCAND; k <<= 1) {
        for (int j = k >> 1; j > 0; j >>= 1) {
#pragma unroll
            for (int s = 0; s < KCAND / 1024; ++s) {
                int p = t + s * 1024;
                int q = p ^ j;
                if (q > p) {
                    unsigned long long a = key[p], bb = key[q];
                    bool desc = ((p & k) == 0);
                    if (desc ? (a < bb) : (a > bb)) { key[p] = bb; key[q] = a; }
                }
            }
            __syncthreads();
        }
    }
    for (int i = t; i < KCAND; i += 1024) {
        unsigned long long kk = key[i];
        size_t o = (size_t)b * KCAND + i;
        if (kk != 0ULL) {
            unsigned n = 0xFFFFFFFFu - (unsigned)(kk & 0xFFFFFFFFu);
            sscore[o] = __uint_as_float((unsigned)(kk >> 32));
            slab[o] = (int)ws_label[(size_t)b * NA + n];
            float4 a4 = ((const float4*)anc)[n];
            float4 r4 = ((const float4*)reg)[(size_t)b * NA + n];
            sbox[o] = decode_clip(a4, r4);
        } else {
            sscore[o] = 0.0f;
            slab[o] = -1;
            sbox[o] = make_float4(0.f, 0.f, 0.f, 0.f);
        }
    }
}

// Pairwise suppression bitmask: block = 8 rows x 32 words; thread = 64 IoUs.
__global__ __launch_bounds__(256) void k_mask(const float4* __restrict__ sbox,
                                              unsigned long long* __restrict__ mask) {
    __shared__ float4 bx[KCAND];  // 32 KB
    int b = blockIdx.y, t = threadIdx.x;
    for (int i = t; i < KCAND; i += 256) bx[i] = sbox[(size_t)b * KCAND + i];
    __syncthreads();
    int r = t >> 5, w = t & 31;
    int row = blockIdx.x * 8 + r;
    float4 rb = bx[row];
    unsigned long long bits = 0ULL;
    {
#pragma clang fp contract(off)
        float areaR = (rb.z - rb.x) * (rb.w - rb.y);
        int cbase = w * 64;
        for (int cc = 0; cc < 64; ++cc) {
            float4 cb = bx[cbase + cc];
            float x1 = fmaxf(rb.x, cb.x), y1 = fmaxf(rb.y, cb.y);
            float x2 = fminf(rb.z, cb.z), y2 = fminf(rb.w, cb.w);
            float inter = fmaxf(x2 - x1, 0.0f) * fmaxf(y2 - y1, 0.0f);
            float areaC = (cb.z - cb.x) * (cb.w - cb.y);
            float iou = inter / (areaR + areaC - inter + 1e-8f);
            if (iou > IOUT) bits |= (1ULL << cc);
        }
    }
    mask[((size_t)b * KCAND + row) * MASK_WORDS + w] = bits;
}

// One block per image; wave 0 does the greedy scan via register bitmask (lane l
// owns removed word l). First SROWS mask rows are staged into LDS by all 256
// threads (picks concentrate at low indices since candidates are score-sorted),
// so the per-pick dependent row load is ~LDS latency instead of cross-XCD L2/L3.
__global__ __launch_bounds__(256) void k_scan(const unsigned long long* __restrict__ mask,
                                              const unsigned* __restrict__ cnt,
                                              const float* __restrict__ sscore,
                                              const int* __restrict__ slab,
                                              const float4* __restrict__ sbox,
                                              float* __restrict__ out) {
    __shared__ unsigned long long lmask[SROWS * MASK_WORDS];  // 126 KB
    __shared__ int picks[MAXDET];
    __shared__ int np_s;
    int b = blockIdx.x, t = threadIdx.x;
    const unsigned long long* mb = mask + (size_t)b * KCAND * MASK_WORDS;

    // stage first SROWS rows (contiguous copy, float4 = 16B/lane)
    float4* l4 = (float4*)lmask;
    const float4* m4 = (const float4*)mb;
    for (int i = t; i < SROWS * MASK_WORDS / 2; i += 256) l4[i] = m4[i];
    __syncthreads();

    if (t < 64) {
        int l = t;
        unsigned M = min(cnt[b], (unsigned)KCAND);
        unsigned long long valid = 0ULL;
        if (l < 32) {
            int rem = (int)M - l * 64;
            valid = (rem >= 64) ? ~0ULL : ((rem > 0) ? ((1ULL << rem) - 1ULL) : 0ULL);
        }
        unsigned long long removed = 0ULL;
        int np = 0;
        while (np < MAXDET) {
            unsigned long long free_ = valid & ~removed;
            unsigned long long act = __ballot(free_ != 0ULL);
            if (act == 0ULL) break;
            int lstar = __ffsll((long long)act) - 1;
            unsigned long long fw = __shfl(free_, lstar, 64);
            int bit = __ffsll((long long)fw) - 1;
            int c = lstar * 64 + bit;
            if (l == 0) picks[np] = c;
            np++;
            if (l == lstar) removed |= (1ULL << bit);  // self-kill (zero-area safe)
            if (l < 32) {
                unsigned long long rw;
                if (c < SROWS) rw = lmask[c * MASK_WORDS + l];   // uniform branch
                else rw = mb[(size_t)c * MASK_WORDS + l];
                removed |= rw;
            }
        }
        if (l == 0) np_s = np;
    }
    __syncthreads();

    int np = np_s;
    for (int k = t; k < MAXDET; k += 256) {
        float sc = 0.0f, lb = -1.0f;
        float4 bb = make_float4(0.f, 0.f, 0.f, 0.f);
        if (k < np) {
            int i = picks[k];
            size_t o = (size_t)b * KCAND + i;
            sc = sscore[o];
            lb = (float)slab[o];
            bb = sbox[o];
        }
        out[b * MAXDET + k] = sc;
        out[NB * MAXDET + b * MAXDET + k] = lb;
        ((float4*)(out + 2 * NB * MAXDET))[b * MAXDET + k] = bb;
    }
}

extern "C" void kernel_launch(void* const* d_in, const int* in_sizes, int n_in,
                              void* d_out, int out_size, void* d_ws, size_t ws_size,
                              hipStream_t stream) {
    const float* reg = (const float*)d_in[0];  // [8,100000,4]
    const float* cls = (const float*)d_in[1];  // [8,100000,90]
    const float* anc = (const float*)d_in[2];  // [1,100000,4]

    char* ws = (char*)d_ws;
    float* ws_score           = (float*)(ws + OFF_SCORE);
    unsigned char* ws_label   = (unsigned char*)(ws + OFF_LABEL);
    unsigned* hrows           = (unsigned*)(ws + OFF_HROWS);
    unsigned* thr_bin         = (unsigned*)(ws + OFF_THR);
    unsigned* cnt             = (unsigned*)(ws + OFF_CNT);
    unsigned long long* ckey  = (unsigned long long*)(ws + OFF_CKEY);
    float* sscore             = (float*)(ws + OFF_SSC);
    int* slab                 = (int*)(ws + OFF_SLAB);
    float4* sbox              = (float4*)(ws + OFF_SBOX);
    unsigned long long* maskp = (unsigned long long*)(ws + OFF_MASK);

    float* out = (float*)d_out;

    k_score_box<<<NB * NA / ABLK, 256, 0, stream>>>(cls, ws_score, ws_label);
    k_hist<<<dim3(NBLK, NB), 256, 0, stream>>>(ws_score, hrows);
    k_thresh<<<NB, 256, 0, stream>>>(hrows, thr_bin, cnt);
    k_compact<<<dim3(NBLK, NB), 256, 0, stream>>>(ws_score, thr_bin, cnt, ckey);
    k_sortdecode<<<NB, 1024, 0, stream>>>(ckey, cnt, ws_label, reg, anc, sscore, slab, sbox);
    k_mask<<<dim3(KCAND / 8, NB), 256, 0, stream>>>(sbox, maskp);
    k_scan<<<NB, 256, 0, stream>>>(maskp, cnt, sscore, slab, sbox, out);
}

// Round 2
// 564.880 us; speedup vs baseline: 1.0244x; 1.0026x over previous
//
#include <hip/hip_runtime.h>

#define NB 8
#define NA 100000
#define NC 90
#define MAXDET 100
#define KCAND 2048
#define NBINS 4096
#define ABLK 64        // anchors per score_box block (22.5 KB LDS -> 7 blocks/CU)
#define MASK_WORDS 32  // u64 words per mask row (2048 bits)
#define SROWS 504      // mask rows staged in LDS by k_scan (126 KB)
#define CONF 0.25f
#define IOUT 0.45f

// ---- workspace layout (bytes) ----
static constexpr size_t OFF_SCORE = 0;                                           // NB*NA f32
static constexpr size_t OFF_LABEL = OFF_SCORE + (size_t)NB * NA * 4;             // NB*NA u8
static constexpr size_t OFF_THR   = OFF_LABEL + (size_t)NB * NA;                 // (unused pad)
static constexpr size_t OFF_CNT   = OFF_THR + 64;                                // NB u32 (pad 64)
static constexpr size_t OFF_CKEY  = OFF_CNT + 64;                                // NB*KCAND u64
static constexpr size_t OFF_SSC   = OFF_CKEY + (size_t)NB * KCAND * 8;           // NB*KCAND f32
static constexpr size_t OFF_SLAB  = OFF_SSC + (size_t)NB * KCAND * 4;            // NB*KCAND i32
static constexpr size_t OFF_SBOX  = OFF_SLAB + (size_t)NB * KCAND * 4;           // NB*KCAND float4
static constexpr size_t OFF_MASK  = OFF_SBOX + (size_t)NB * KCAND * 16;          // NB*KCAND*32 u64

__device__ __forceinline__ float4 decode_clip(float4 a, float4 r) {
#pragma clang fp contract(off)
    // a = (y1,x1,y2,x2) anchor; r = (dy,dx,dh,dw)
    float yca = (a.x + a.z) * 0.5f;
    float xca = (a.y + a.w) * 0.5f;
    float ha  = a.z - a.x;
    float wa  = a.w - a.y;
    float w   = expf(r.w) * wa;
    float h   = expf(r.z) * ha;
    float yc  = r.x * ha + yca;
    float xc  = r.y * wa + xca;
    float x1  = xc - w * 0.5f, y1 = yc - h * 0.5f;
    float x2  = xc + w * 0.5f, y2 = yc + h * 0.5f;
    x1 = fminf(fmaxf(x1, 0.0f), 512.0f);
    x2 = fminf(fmaxf(x2, 0.0f), 512.0f);
    y1 = fminf(fmaxf(y1, 0.0f), 512.0f);
    y2 = fminf(fmaxf(y2, 0.0f), 512.0f);
    return make_float4(x1, y1, x2, y2);
}

// LDS-transpose score kernel. Sigmoid is strictly monotonic, so the per-class
// reduction runs on RAW LOGITS via an order-preserving bit transform; exactly ONE
// sigmoid per anchor is computed on the winning logit (bit-identical scores).
__global__ __launch_bounds__(256) void k_score_box(const float* __restrict__ cls,
                                                   float* __restrict__ ws_score,
                                                   unsigned char* __restrict__ ws_label) {
    __shared__ float tile[ABLK * NC];  // 22.5 KB
    int t = threadIdx.x;
    const float4* g4 = (const float4*)(cls + (size_t)blockIdx.x * (ABLK * NC));
    float4* t4 = (float4*)tile;
#pragma unroll
    for (int i = t; i < ABLK * NC / 4; i += 256) t4[i] = g4[i];
    __syncthreads();

    int la = t >> 2, h = t & 3;
    int off = h * 22 + (h < 2 ? h : 2);  // 0,23,46,68
    int len = (h < 2) ? 23 : 22;
    const float* row = tile + la * NC + off;
    // order-preserving unsigned encoding of float: pos -> u|0x80000000, neg -> ~u
    unsigned bord = 0u;
    int bci = 0;
    for (int i = 0; i < len; ++i) {
        unsigned u = __float_as_uint(row[i]);
        unsigned ord = u ^ (0x80000000u | (unsigned)((int)u >> 31));
        if (ord > bord) { bord = ord; bci = off + i; }  // strict > keeps first (lowest class)
    }
    unsigned long long best =
        ((unsigned long long)bord << 32) | (unsigned long long)(unsigned)(NC - 1 - bci);
    unsigned long long o = __shfl_xor(best, 1, 64);
    if (o > best) best = o;
    o = __shfl_xor(best, 2, 64);
    if (o > best) best = o;
    if (h == 0) {
        int a = blockIdx.x * ABLK + la;
        unsigned ordv = (unsigned)(best >> 32);
        unsigned u = (ordv & 0x80000000u) ? (ordv ^ 0x80000000u) : ~ordv;
        float x = __uint_as_float(u);
        float s = 1.0f / (1.0f + expf(-x));  // same formula as verified rounds 2-4
        ws_score[a] = s;
        ws_label[a] = (unsigned char)(NC - 1 - (unsigned)(best & 0xFFFFFFFFu));
    }
}

// Fused hist + threshold + compact: one block per image (replaces 3 kernels and
// the hrows round-trip). Pass 1: LDS hist. Phase 2: suffix-scan -> thr bin.
// Pass 3: block-wide scan compact into packed keys (deterministic, no atomics).
__global__ __launch_bounds__(1024) void k_select(const float* __restrict__ ws_score,
                                                 unsigned* __restrict__ cnt,
                                                 unsigned long long* __restrict__ ckey) {
    __shared__ unsigned hist[NBINS];   // 16 KB
    __shared__ unsigned chunk[256];
    __shared__ unsigned sscan[1024];   // 4 KB
    __shared__ int bstar;
    int b = blockIdx.x, t = threadIdx.x;
    const float* sc = ws_score + (size_t)b * NA;

    for (int i = t; i < NBINS; i += 1024) hist[i] = 0u;
    if (t == 0) bstar = NBINS - 1;
    __syncthreads();
    for (int i = t; i < NA; i += 1024) {
        float s = sc[i];
        if (s > CONF) {
            int bin = min((int)(s * (float)NBINS), NBINS - 1);
            atomicAdd(&hist[bin], 1u);
        }
    }
    __syncthreads();
    if (t < 256) {
        unsigned s = 0;
        for (int j = 0; j < 16; ++j) s += hist[t * 16 + j];
        chunk[t] = s;
    }
    __syncthreads();
    if (t < 256) {
        unsigned U = 0;
        for (int j = t + 1; j < 256; ++j) U += chunk[j];
        unsigned run = U;
        int cand = NBINS;
        for (int j = 15; j >= 0; --j) {
            run += hist[t * 16 + j];
            if (run <= (unsigned)KCAND) cand = t * 16 + j;
        }
        if (cand < NBINS) atomicMin(&bstar, cand);
    }
    __syncthreads();
    unsigned thr = (unsigned)bstar;

    unsigned c = 0;
    for (int i = t; i < NA; i += 1024) {
        float s = sc[i];
        if (s > CONF) {
            int bin = min((int)(s * (float)NBINS), NBINS - 1);
            if ((unsigned)bin >= thr) c++;
        }
    }
    sscan[t] = c;
    __syncthreads();
    for (int off = 1; off < 1024; off <<= 1) {
        unsigned v = (t >= off) ? sscan[t - off] : 0u;
        __syncthreads();
        sscan[t] += v;
        __syncthreads();
    }
    unsigned pos = sscan[t] - c;  // exclusive prefix
    for (int i = t; i < NA; i += 1024) {
        float s = sc[i];
        if (s > CONF) {
            int bin = min((int)(s * (float)NBINS), NBINS - 1);
            if ((unsigned)bin >= thr) {
                unsigned p = pos++;
                if (p < (unsigned)KCAND)
                    ckey[(size_t)b * KCAND + p] =
                        ((unsigned long long)__float_as_uint(s) << 32) |
                        (unsigned long long)(0xFFFFFFFFu - (unsigned)i);
            }
        }
    }
    if (t == 1023) cnt[b] = sscan[1023];
}

// One 1024-thread block per image: bitonic sort 2048 keys descending (16 waves to
// amortize the 66 barriers), then decode surviving boxes.
__global__ __launch_bounds__(1024) void k_sortdecode(const unsigned long long* __restrict__ ckey,
                                                     const unsigned* __restrict__ cnt,
                                                     const unsigned char* __restrict__ ws_label,
                                                     const float* __restrict__ reg,
                                                     const float* __restrict__ anc,
                                                     float* __restrict__ sscore,
                                                     int* __restrict__ slab,
                                                     float4* __restrict__ sbox) {
    __shared__ unsigned long long key[KCAND];  // 16 KB
    int b = blockIdx.x, t = threadIdx.x;
    unsigned M = min(cnt[b], (unsigned)KCAND);
    for (int i = t; i < KCAND; i += 1024)
        key[i] = (i < (int)M) ? ckey[(size_t)b * KCAND + i] : 0ULL;
    __syncthreads();
    for (int k = 2; k <= KCAND; k <<= 1) {
        for (int j = k >> 1; j > 0; j >>= 1) {
#pragma unroll
            for (int s = 0; s < KCAND / 1024; ++s) {
                int p = t + s * 1024;
                int q = p ^ j;
                if (q > p) {
                    unsigned long long a = key[p], bb = key[q];
                    bool desc = ((p & k) == 0);
                    if (desc ? (a < bb) : (a > bb)) { key[p] = bb; key[q] = a; }
                }
            }
            __syncthreads();
        }
    }
    for (int i = t; i < KCAND; i += 1024) {
        unsigned long long kk = key[i];
        size_t o = (size_t)b * KCAND + i;
        if (kk != 0ULL) {
            unsigned n = 0xFFFFFFFFu - (unsigned)(kk & 0xFFFFFFFFu);
            sscore[o] = __uint_as_float((unsigned)(kk >> 32));
            slab[o] = (int)ws_label[(size_t)b * NA + n];
            float4 a4 = ((const float4*)anc)[n];
            float4 r4 = ((const float4*)reg)[(size_t)b * NA + n];
            sbox[o] = decode_clip(a4, r4);
        } else {
            sscore[o] = 0.0f;
            slab[o] = -1;
            sbox[o] = make_float4(0.f, 0.f, 0.f, 0.f);
        }
    }
}

// Pairwise suppression bitmask. Lane map = (8 rows x 8 contiguous words)/wave so
// lower-triangle words skip at wave granularity (greedy scan never consults
// col <= row: all j < picked c are already removed). Column start rotated by
// word-id so LDS b128 reads spread across all 8 bank groups (was 32-way conflict).
__global__ __launch_bounds__(256) void k_mask(const float4* __restrict__ sbox,
                                              unsigned long long* __restrict__ mask) {
    __shared__ float4 bx[KCAND];  // 32 KB
    int b = blockIdx.y, t = threadIdx.x;
    for (int i = t; i < KCAND; i += 256) bx[i] = sbox[(size_t)b * KCAND + i];
    __syncthreads();
    int r = t & 7, w = t >> 3;
    int row = blockIdx.x * 8 + r;
    int cbase = w * 64;
    unsigned long long bits = 0ULL;
    if (cbase + 63 >= row) {
#pragma clang fp contract(off)
        float4 rb = bx[row];
        float areaR = (rb.z - rb.x) * (rb.w - rb.y);
        for (int k = 0; k < 64; ++k) {
            int cc = (k + w) & 63;  // per-word rotation: conflict-free LDS
            float4 cb = bx[cbase + cc];
            float x1 = fmaxf(rb.x, cb.x), y1 = fmaxf(rb.y, cb.y);
            float x2 = fminf(rb.z, cb.z), y2 = fminf(rb.w, cb.w);
            float inter = fmaxf(x2 - x1, 0.0f) * fmaxf(y2 - y1, 0.0f);
            float areaC = (cb.z - cb.x) * (cb.w - cb.y);
            float iou = inter / (areaR + areaC - inter + 1e-8f);
            if (iou > IOUT) bits |= (1ULL << cc);
        }
    }
    mask[((size_t)b * KCAND + row) * MASK_WORDS + w] = bits;
}

// One block per image; wave 0 does the greedy scan via register bitmask (lane l
// owns removed word l). First SROWS mask rows are staged into LDS by all 256
// threads (picks concentrate at low indices since candidates are score-sorted).
__global__ __launch_bounds__(256) void k_scan(const unsigned long long* __restrict__ mask,
                                              const unsigned* __restrict__ cnt,
                                              const float* __restrict__ sscore,
                                              const int* __restrict__ slab,
                                              const float4* __restrict__ sbox,
                                              float* __restrict__ out) {
    __shared__ unsigned long long lmask[SROWS * MASK_WORDS];  // 126 KB
    __shared__ int picks[MAXDET];
    __shared__ int np_s;
    int b = blockIdx.x, t = threadIdx.x;
    const unsigned long long* mb = mask + (size_t)b * KCAND * MASK_WORDS;

    float4* l4 = (float4*)lmask;
    const float4* m4 = (const float4*)mb;
    for (int i = t; i < SROWS * MASK_WORDS / 2; i += 256) l4[i] = m4[i];
    __syncthreads();

    if (t < 64) {
        int l = t;
        unsigned M = min(cnt[b], (unsigned)KCAND);
        unsigned long long valid = 0ULL;
        if (l < 32) {
            int rem = (int)M - l * 64;
            valid = (rem >= 64) ? ~0ULL : ((rem > 0) ? ((1ULL << rem) - 1ULL) : 0ULL);
        }
        unsigned long long removed = 0ULL;
        int np = 0;
        while (np < MAXDET) {
            unsigned long long free_ = valid & ~removed;
            unsigned long long act = __ballot(free_ != 0ULL);
            if (act == 0ULL) break;
            int lstar = __ffsll((long long)act) - 1;
            unsigned long long fw = __shfl(free_, lstar, 64);
            int bit = __ffsll((long long)fw) - 1;
            int c = lstar * 64 + bit;
            if (l == 0) picks[np] = c;
            np++;
            if (l == lstar) removed |= (1ULL << bit);  // self-kill (zero-area safe)
            if (l < 32) {
                unsigned long long rw;
                if (c < SROWS) rw = lmask[c * MASK_WORDS + l];  // uniform branch
                else rw = mb[(size_t)c * MASK_WORDS + l];
                removed |= rw;
            }
        }
        if (l == 0) np_s = np;
    }
    __syncthreads();

    int np = np_s;
    for (int k = t; k < MAXDET; k += 256) {
        float sc = 0.0f, lb = -1.0f;
        float4 bb = make_float4(0.f, 0.f, 0.f, 0.f);
        if (k < np) {
            int i = picks[k];
            size_t o = (size_t)b * KCAND + i;
            sc = sscore[o];
            lb = (float)slab[o];
            bb = sbox[o];
        }
        out[b * MAXDET + k] = sc;
        out[NB * MAXDET + b * MAXDET + k] = lb;
        ((float4*)(out + 2 * NB * MAXDET))[b * MAXDET + k] = bb;
    }
}

extern "C" void kernel_launch(void* const* d_in, const int* in_sizes, int n_in,
                              void* d_out, int out_size, void* d_ws, size_t ws_size,
                              hipStream_t stream) {
    const float* reg = (const float*)d_in[0];  // [8,100000,4]
    const float* cls = (const float*)d_in[1];  // [8,100000,90]
    const float* anc = (const float*)d_in[2];  // [1,100000,4]

    char* ws = (char*)d_ws;
    float* ws_score           = (float*)(ws + OFF_SCORE);
    unsigned char* ws_label   = (unsigned char*)(ws + OFF_LABEL);
    unsigned* cnt             = (unsigned*)(ws + OFF_CNT);
    unsigned long long* ckey  = (unsigned long long*)(ws + OFF_CKEY);
    float* sscore             = (float*)(ws + OFF_SSC);
    int* slab                 = (int*)(ws + OFF_SLAB);
    float4* sbox              = (float4*)(ws + OFF_SBOX);
    unsigned long long* maskp = (unsigned long long*)(ws + OFF_MASK);

    float* out = (float*)d_out;

    k_score_box<<<NB * NA / ABLK, 256, 0, stream>>>(cls, ws_score, ws_label);
    k_select<<<NB, 1024, 0, stream>>>(ws_score, cnt, ckey);
    k_sortdecode<<<NB, 1024, 0, stream>>>(ckey, cnt, ws_label, reg, anc, sscore, slab, sbox);
    k_mask<<<dim3(KCAND / 8, NB), 256, 0, stream>>>(sbox, maskp);
    k_scan<<<NB, 256, 0, stream>>>(maskp, cnt, sscore, slab, sbox, out);
}